// Round 3
// baseline (849.391 us; speedup 1.0000x reference)
//
#include <hip/hip_runtime.h>
#include <hip/hip_bf16.h>
#include <math.h>

typedef __hip_bfloat16 bf16;

__device__ __forceinline__ float b2f(const bf16 v) { return __bfloat162float(v); }
__device__ __forceinline__ bf16 f2b(const float v) { return __float2bfloat16(v); }

// dtype-flexible load/store: f32 flag selects float32 vs bfloat16 interpretation
__device__ __forceinline__ float ldsel(const void* p, size_t i, int f32) {
  return f32 ? ((const float*)p)[i] : b2f(((const bf16*)p)[i]);
}
__device__ __forceinline__ void stsel(void* p, size_t i, float v, int f32) {
  if (f32) ((float*)p)[i] = v; else ((bf16*)p)[i] = f2b(v);
}

#define NN 3712          // nodes
#define NE 37120         // edges (without self loops)
#define NG 32            // graphs
#define NREG 116         // nodes per graph
#define MAXDEG 48        // bucket capacity (in-degree ~ Poisson(10); P(>48) ~ 1e-18)

// ---------------- dtype detector ----------------
// Reads tensors AS bf16. Real bf16 data: finite, |x| < ~5. fp32 data misread as
// bf16: low-mantissa halves have random exponents -> NaN/Inf/huge values certain
// among 4096 samples. flags[0]=features are f32, flags[1]=weights are f32.
__global__ __launch_bounds__(256) void k_detect(const void* nf, const void* w0, int* flags) {
  __shared__ int bad[2];
  if (threadIdx.x < 2) bad[threadIdx.x] = 0;
  __syncthreads();
  const bf16* a = (const bf16*)nf;
  const bf16* b = (const bf16*)w0;
  int l0 = 0, l1 = 0;
  for (int i = threadIdx.x; i < 4096; i += 256) {
    float x = b2f(a[i]); if (!(fabsf(x) < 1e4f)) l0++;   // catches NaN/Inf too
    float y = b2f(b[i]); if (!(fabsf(y) < 1e4f)) l1++;
  }
  if (l0) atomicAdd(&bad[0], l0);
  if (l1) atomicAdd(&bad[1], l1);
  __syncthreads();
  if (threadIdx.x == 0) { flags[0] = bad[0] > 0; flags[1] = bad[1] > 0; }
}

// ---------------- utility kernels ----------------
__global__ __launch_bounds__(256) void k_zero(int* __restrict__ p, int n) {
  int i = blockIdx.x * 256 + threadIdx.x;
  if (i < n) p[i] = 0;
}

__global__ __launch_bounds__(256) void k_scatter(const int* __restrict__ src, const int* __restrict__ dst,
                                                 int* __restrict__ cnt, int* __restrict__ bucket, int E) {
  int e = blockIdx.x * 256 + threadIdx.x;
  if (e < E) {
    int d = dst[e], s = src[e];
    if ((unsigned)d < NN && (unsigned)s < NN) {     // defensive: never OOB
      int p = atomicAdd(&cnt[d], 1);
      if (p < MAXDEG) bucket[d * MAXDEG + p] = s;
    }
  }
}

// ---------------- tiled GEMM: C[MxN](f32-acc -> bf16) = A[MxK] * B[KxN] ----------------
// aMode/bMode: -1 = operand is internal bf16; >=0 = flags[mode] selects f32/bf16.
__global__ __launch_bounds__(256) void k_gemm(const void* __restrict__ A, const void* __restrict__ B,
                                              bf16* __restrict__ C, int M, int N, int K,
                                              const int* __restrict__ flags, int aMode, int bMode) {
  int aF = aMode < 0 ? 0 : flags[aMode];
  int bF = bMode < 0 ? 0 : flags[bMode];
  __shared__ float As[16][68];
  __shared__ float Bs[16][68];
  int tid = threadIdx.x;
  int m0 = blockIdx.y * 64, n0 = blockIdx.x * 64;
  int tx = tid & 15, ty = tid >> 4;      // compute layout: 16x16 threads, 4x4 micro-tile
  int bk = tid >> 6, bn = tid & 63;      // B load layout
  float acc[4][4] = {};
  for (int k0 = 0; k0 < K; k0 += 16) {
#pragma unroll
    for (int i = 0; i < 4; ++i) {
      int r = ty + i * 16;
      As[tx][r] = ldsel(A, (size_t)(m0 + r) * K + (k0 + tx), aF);
    }
#pragma unroll
    for (int i = 0; i < 4; ++i) {
      int kk = bk + i * 4;
      Bs[kk][bn] = ldsel(B, (size_t)(k0 + kk) * N + (n0 + bn), bF);
    }
    __syncthreads();
#pragma unroll
    for (int k = 0; k < 16; ++k) {
      float a[4], b[4];
#pragma unroll
      for (int i = 0; i < 4; ++i) a[i] = As[k][ty * 4 + i];
#pragma unroll
      for (int j = 0; j < 4; ++j) b[j] = Bs[k][tx * 4 + j];
#pragma unroll
      for (int i = 0; i < 4; ++i)
#pragma unroll
        for (int j = 0; j < 4; ++j)
          acc[i][j] = fmaf(a[i], b[j], acc[i][j]);
    }
    __syncthreads();
  }
#pragma unroll
  for (int i = 0; i < 4; ++i) {
    int m = m0 + ty * 4 + i;
#pragma unroll
    for (int j = 0; j < 4; ++j)
      C[(size_t)m * N + n0 + tx * 4 + j] = f2b(acc[i][j]);
  }
}

// ---------------- attention coefficients al/ar: (N,8) ----------------
__global__ __launch_bounds__(256) void k_attn(const bf16* __restrict__ H, const void* __restrict__ a_s,
                                              const void* __restrict__ a_d, float* __restrict__ al,
                                              float* __restrict__ ar, int C, const int* __restrict__ flags) {
  int wF = flags[1];
  int n = blockIdx.x;
  int lane = threadIdx.x & 63, wave = threadIdx.x >> 6;
  int D = 8 * C;
#pragma unroll
  for (int u = 0; u < 2; ++u) {
    int hd = wave * 2 + u;
    float ps = 0.f, pd = 0.f;
    for (int c = lane; c < C; c += 64) {
      float h = b2f(H[(size_t)n * D + hd * C + c]);
      ps = fmaf(h, ldsel(a_s, hd * C + c, wF), ps);
      pd = fmaf(h, ldsel(a_d, hd * C + c, wF), pd);
    }
#pragma unroll
    for (int off = 32; off; off >>= 1) { ps += __shfl_down(ps, off); pd += __shfl_down(pd, off); }
    if (lane == 0) { al[n * 8 + hd] = ps; ar[n * 8 + hd] = pd; }
  }
}

// ---------------- per-dst softmax + aggregation + bias + ELU + LayerNorm ----------------
__global__ __launch_bounds__(256) void k_agg(const bf16* __restrict__ H, const float* __restrict__ al,
                                             const float* __restrict__ ar, const int* __restrict__ cnt,
                                             const int* __restrict__ bucket, const void* __restrict__ bias,
                                             const void* __restrict__ ls, const void* __restrict__ lb,
                                             bf16* __restrict__ Xout, int C, int concat,
                                             const int* __restrict__ flags) {
  int wF = flags[1];
  int d = blockIdx.x;
  int t = threadIdx.x;
  int lane = t & 63, wave = t >> 6;
  int D = 8 * C;
  __shared__ int sid[MAXDEG + 1];
  __shared__ float w[8][MAXDEG + 2];
  __shared__ float vals[2048];
  __shared__ float r1[4], r2[4];
  __shared__ float sMu, sRs;

  int deg = cnt[d]; deg = deg > MAXDEG ? MAXDEG : deg;
  if (t < deg) sid[t] = bucket[d * MAXDEG + t];
  if (t == deg) sid[deg] = d;                 // self loop (PyG appends it always)
  __syncthreads();
  int total = deg + 1;

  if (t < 8) {   // per-head segment softmax over incoming edges
    float ard = ar[d * 8 + t];
    float m = -1e30f;
    for (int e = 0; e < total; ++e) {
      float lg = al[sid[e] * 8 + t] + ard;
      lg = lg > 0.f ? lg : 0.2f * lg;         // leaky_relu(0.2)
      w[t][e] = lg;
      m = fmaxf(m, lg);
    }
    float den = 0.f;
    for (int e = 0; e < total; ++e) { float x = expf(w[t][e] - m); w[t][e] = x; den += x; }
    float inv = 1.f / den;
    for (int e = 0; e < total; ++e) w[t][e] *= inv;
  }
  __syncthreads();

  for (int i = t; i < D; i += 256) {
    int hd = i / C;
    float acc = 0.f;
    for (int e = 0; e < total; ++e) acc = fmaf(w[hd][e], b2f(H[(size_t)sid[e] * D + i]), acc);
    vals[i] = acc;
  }
  __syncthreads();

  if (concat) {
    float loc[8];
    float s1 = 0.f, s2 = 0.f;
    int nl = 0;
    for (int i = t; i < D; i += 256) {
      float v = vals[i] + ldsel(bias, i, wF);
      v = v > 0.f ? v : expf(v) - 1.f;        // ELU
      loc[nl++] = v; s1 += v; s2 += v * v;
    }
#pragma unroll
    for (int off = 32; off; off >>= 1) { s1 += __shfl_down(s1, off); s2 += __shfl_down(s2, off); }
    if (lane == 0) { r1[wave] = s1; r2[wave] = s2; }
    __syncthreads();
    if (t == 0) {
      float S1 = r1[0] + r1[1] + r1[2] + r1[3];
      float S2 = r2[0] + r2[1] + r2[2] + r2[3];
      float mu = S1 / D;
      sMu = mu; sRs = rsqrtf(S2 / D - mu * mu + 1e-5f);
    }
    __syncthreads();
    nl = 0;
    for (int i = t; i < D; i += 256) {
      float v = loc[nl++];
      Xout[(size_t)d * D + i] = f2b((v - sMu) * sRs * ldsel(ls, i, wF) + ldsel(lb, i, wF));
    }
  } else {
    if (t < 64) {   // wave 0 only: mean over 8 heads -> 64 dims, ELU, LN over 64
      float v = 0.f;
#pragma unroll
      for (int h = 0; h < 8; ++h) v += vals[h * 64 + t];
      v = v * 0.125f + ldsel(bias, t, wF);
      v = v > 0.f ? v : expf(v) - 1.f;
      float s1 = v, s2 = v * v;
#pragma unroll
      for (int off = 32; off; off >>= 1) { s1 += __shfl_xor(s1, off); s2 += __shfl_xor(s2, off); }
      float mu = s1 * (1.f / 64.f);
      float var = s2 * (1.f / 64.f) - mu * mu;
      float rs = rsqrtf(var + 1e-5f);
      Xout[(size_t)d * 64 + t] = f2b((v - mu) * rs * ldsel(ls, t, wF) + ldsel(lb, t, wF));
    }
  }
}

// ---------------- projection (64->256) + LN + GELU(erf) + q ----------------
__global__ __launch_bounds__(256) void k_proj(const bf16* __restrict__ X3, const void* __restrict__ wp,
                                              const void* __restrict__ bp, const void* __restrict__ lsp,
                                              const void* __restrict__ lbp, const void* __restrict__ wq,
                                              const void* __restrict__ bq,
                                              float* __restrict__ q, void* __restrict__ dout,
                                              const int* __restrict__ flags) {
  int wF = flags[1], xF = flags[0];
  int n = blockIdx.x, t = threadIdx.x;
  int lane = t & 63, wave = t >> 6;
  __shared__ float xs[64];
  __shared__ float r1[4], r2[4];
  __shared__ float sMu, sRs;
  if (t < 64) xs[t] = b2f(X3[n * 64 + t]);
  __syncthreads();
  float y = ldsel(bp, t, wF);
#pragma unroll 8
  for (int k = 0; k < 64; ++k) y = fmaf(xs[k], ldsel(wp, k * 256 + t, wF), y);
  float s1 = y, s2 = y * y;
#pragma unroll
  for (int off = 32; off; off >>= 1) { s1 += __shfl_down(s1, off); s2 += __shfl_down(s2, off); }
  if (lane == 0) { r1[wave] = s1; r2[wave] = s2; }
  __syncthreads();
  if (t == 0) {
    float S1 = r1[0] + r1[1] + r1[2] + r1[3];
    float S2 = r2[0] + r2[1] + r2[2] + r2[3];
    float mu = S1 / 256.f;
    sMu = mu; sRs = rsqrtf(S2 / 256.f - mu * mu + 1e-5f);
  }
  __syncthreads();
  float v = (y - sMu) * sRs * ldsel(lsp, t, wF) + ldsel(lbp, t, wF);
  float g = 0.5f * v * (1.f + erff(v * 0.70710678118654752f));   // exact GELU
  stsel(dout, (size_t)NG * 256 + (size_t)n * 256 + t, g, xF);    // node_out
  float qv = g * ldsel(wq, t, wF);
#pragma unroll
  for (int off = 32; off; off >>= 1) qv += __shfl_down(qv, off);
  if (lane == 0) r1[wave] = qv;
  __syncthreads();
  if (t == 0) q[n] = r1[0] + r1[1] + r1[2] + r1[3] + ldsel(bq, 0, wF);
}

// ---------------- attention pooling per graph ----------------
// global-softmax denominator cancels in num/den => per-graph softmax is exact-equivalent.
__global__ __launch_bounds__(256) void k_pool(void* __restrict__ dout, const float* __restrict__ q,
                                              const int* __restrict__ flags) {
  int xF = flags[0];
  int b = blockIdx.x, t = threadIdx.x;
  __shared__ float es[NREG];
  __shared__ float sDen;
  if (t < NREG) es[t] = q[b * NREG + t];
  __syncthreads();
  if (t == 0) {
    float m = -1e30f;
    for (int i = 0; i < NREG; ++i) m = fmaxf(m, es[i]);
    float den = 0.f;
    for (int i = 0; i < NREG; ++i) { float e = expf(es[i] - m); es[i] = e; den += e; }
    sDen = den;
  }
  __syncthreads();
  float acc = 0.f;
  for (int i = 0; i < NREG; ++i)
    acc = fmaf(es[i], ldsel(dout, (size_t)NG * 256 + (size_t)(b * NREG + i) * 256 + t, xF), acc);
  stsel(dout, (size_t)b * 256 + t, acc / sDen, xF);
}

// ---------------- launcher ----------------
extern "C" void kernel_launch(void* const* d_in, const int* in_sizes, int n_in,
                              void* d_out, int out_size, void* d_ws, size_t ws_size,
                              hipStream_t stream) {
  const void* nf  = d_in[0];
  const int* src  = (const int*)d_in[1];
  const int* dst  = (const int*)d_in[2];
  // d_in[3] = batch (node n belongs to graph n/116 by construction)
  const void *w0 = d_in[4],  *b0 = d_in[5],  *as0 = d_in[6], *ad0 = d_in[7],  *ls0 = d_in[8],  *lb0 = d_in[9];
  const void *w1 = d_in[10], *b1 = d_in[11], *as1 = d_in[12], *ad1 = d_in[13], *ls1 = d_in[14], *lb1 = d_in[15];
  const void *w2 = d_in[16], *b2 = d_in[17], *as2 = d_in[18], *ad2 = d_in[19], *ls2 = d_in[20], *lb2 = d_in[21];
  const void *wp = d_in[22], *bp = d_in[23], *lsp = d_in[24], *lbp = d_in[25], *wq = d_in[26], *bq = d_in[27];

  // workspace layout — TOTAL ~31.4 MB
  int* flags  = (int*)d_ws;                       // 4 ints
  float* al   = (float*)(flags + 4);              // NN*8 f32
  float* ar   = al + NN * 8;                      // NN*8 f32
  int* cnt    = (int*)(ar + NN * 8);              // NN
  int* bucket = cnt + NN;                         // NN*MAXDEG
  float* q    = (float*)(bucket + NN * MAXDEG);   // NN f32
  bf16* X     = (bf16*)(q + NN);                  // NN*2048 bf16
  bf16* Hb    = X + (size_t)NN * 2048;            // NN*2048 bf16

  // stage 0: detect input dtype, build incoming-edge buckets
  k_detect<<<1, 256, 0, stream>>>(nf, w0, flags);
  k_zero<<<(NN + 255) / 256, 256, 0, stream>>>(cnt, NN);
  k_scatter<<<(NE + 255) / 256, 256, 0, stream>>>(src, dst, cnt, bucket, NE);

  // layer 0: 256 -> 8x256 concat (2048); A = node_features directly
  k_gemm<<<dim3(2048 / 64, NN / 64), 256, 0, stream>>>(nf, w0, Hb, NN, 2048, 256, flags, 0, 1);
  k_attn<<<NN, 256, 0, stream>>>(Hb, as0, ad0, al, ar, 256, flags);
  k_agg<<<NN, 256, 0, stream>>>(Hb, al, ar, cnt, bucket, b0, ls0, lb0, X, 256, 1, flags);

  // layer 1: 2048 -> 8x128 concat (1024)
  k_gemm<<<dim3(1024 / 64, NN / 64), 256, 0, stream>>>(X, w1, Hb, NN, 1024, 2048, flags, -1, 1);
  k_attn<<<NN, 256, 0, stream>>>(Hb, as1, ad1, al, ar, 128, flags);
  k_agg<<<NN, 256, 0, stream>>>(Hb, al, ar, cnt, bucket, b1, ls1, lb1, X, 128, 1, flags);

  // layer 2: 1024 -> 8x64 mean (64)
  k_gemm<<<dim3(512 / 64, NN / 64), 256, 0, stream>>>(X, w2, Hb, NN, 512, 1024, flags, -1, 1);
  k_attn<<<NN, 256, 0, stream>>>(Hb, as2, ad2, al, ar, 64, flags);
  k_agg<<<NN, 256, 0, stream>>>(Hb, al, ar, cnt, bucket, b2, ls2, lb2, X, 64, 0, flags);

  // projection + GELU + q, then pooling (node_out lives in d_out)
  k_proj<<<NN, 256, 0, stream>>>(X, wp, bp, lsp, lbp, wq, bq, q, d_out, flags);
  k_pool<<<NG, 256, 0, stream>>>(d_out, q, flags);
}

// Round 4
// 409.986 us; speedup vs baseline: 2.0718x; 2.0718x over previous
//
#include <hip/hip_runtime.h>
#include <hip/hip_bf16.h>
#include <math.h>

typedef __hip_bfloat16 bf16;
typedef short short8 __attribute__((ext_vector_type(8)));
typedef float f32x4 __attribute__((ext_vector_type(4)));

__device__ __forceinline__ float b2f(const bf16 v) { return __bfloat162float(v); }
__device__ __forceinline__ bf16 f2b(const float v) { return __float2bfloat16(v); }

// dtype-flexible load/store: f32 flag selects float32 vs bfloat16 interpretation
__device__ __forceinline__ float ldsel(const void* p, size_t i, int f32) {
  return f32 ? ((const float*)p)[i] : b2f(((const bf16*)p)[i]);
}
__device__ __forceinline__ void stsel(void* p, size_t i, float v, int f32) {
  if (f32) ((float*)p)[i] = v; else ((bf16*)p)[i] = f2b(v);
}

#define NN 3712          // nodes
#define NE 37120         // edges (without self loops)
#define NG 32            // graphs
#define NREG 116         // nodes per graph
#define MAXDEG 48        // bucket capacity (in-degree ~ Poisson(10); P(>48) ~ 1e-18)

// ---------------- dtype detector ----------------
// Reads tensors AS bf16. Real bf16 data: finite, |x| < ~5. fp32 data misread as
// bf16 -> random exponent fields -> NaN/Inf/huge certain among 4096 samples.
__global__ __launch_bounds__(256) void k_detect(const void* nf, const void* w0, int* flags) {
  __shared__ int bad[2];
  if (threadIdx.x < 2) bad[threadIdx.x] = 0;
  __syncthreads();
  const bf16* a = (const bf16*)nf;
  const bf16* b = (const bf16*)w0;
  int l0 = 0, l1 = 0;
  for (int i = threadIdx.x; i < 4096; i += 256) {
    float x = b2f(a[i]); if (!(fabsf(x) < 1e4f)) l0++;
    float y = b2f(b[i]); if (!(fabsf(y) < 1e4f)) l1++;
  }
  if (l0) atomicAdd(&bad[0], l0);
  if (l1) atomicAdd(&bad[1], l1);
  __syncthreads();
  if (threadIdx.x == 0) { flags[0] = bad[0] > 0; flags[1] = bad[1] > 0; }
}

// ---------------- utility kernels ----------------
__global__ __launch_bounds__(256) void k_zero(int* __restrict__ p, int n) {
  int i = blockIdx.x * 256 + threadIdx.x;
  if (i < n) p[i] = 0;
}

__global__ __launch_bounds__(256) void k_scatter(const int* __restrict__ src, const int* __restrict__ dst,
                                                 int* __restrict__ cnt, int* __restrict__ bucket, int E) {
  int e = blockIdx.x * 256 + threadIdx.x;
  if (e < E) {
    int d = dst[e], s = src[e];
    if ((unsigned)d < NN && (unsigned)s < NN) {
      int p = atomicAdd(&cnt[d], 1);
      if (p < MAXDEG) bucket[d * MAXDEG + p] = s;
    }
  }
}

// convert (f32|bf16) -> bf16
__global__ __launch_bounds__(256) void k_tobf16(const void* __restrict__ in, bf16* __restrict__ out,
                                                int n, const int* __restrict__ flags, int fidx) {
  int f = flags[fidx];
  int i = blockIdx.x * 256 + threadIdx.x;
  if (i < n) out[i] = f2b(ldsel(in, i, f));
}

// transpose W[K][N] -> Wt[N][K], output bf16. K,N multiples of 32.
__global__ __launch_bounds__(256) void k_transpose(const void* __restrict__ W, bf16* __restrict__ Wt,
                                                   int K, int N, const int* __restrict__ flags) {
  int f = flags[1];
  __shared__ float tile[32][33];
  int tx = threadIdx.x & 31, ty = threadIdx.x >> 5;   // 32 x 8
  int k0 = blockIdx.x * 32, n0 = blockIdx.y * 32;
#pragma unroll
  for (int i = 0; i < 4; ++i)
    tile[ty + i * 8][tx] = ldsel(W, (size_t)(k0 + ty + i * 8) * N + n0 + tx, f);
  __syncthreads();
#pragma unroll
  for (int i = 0; i < 4; ++i)
    Wt[(size_t)(n0 + ty + i * 8) * K + k0 + tx] = f2b(tile[tx][ty + i * 8]);
}

// ---------------- MFMA bf16 NT GEMM: C[MxN] = A[MxK] * Bt[NxK]^T ----------------
// 128x128 tile, BK=32, 4 waves (2x2), each wave 4x4 tiles of 16x16x32 MFMA.
// LDS rows padded to 40 shorts (80 B): keeps 16B alignment, only 2-way bank aliasing (free).
__global__ __launch_bounds__(256) void k_gemm_mfma(const bf16* __restrict__ A, const bf16* __restrict__ Bt,
                                                   bf16* __restrict__ C, int M, int N, int K) {
  __shared__ short As[128 * 40];
  __shared__ short Bs[128 * 40];
  int tid = threadIdx.x;
  int wave = tid >> 6, lane = tid & 63;
  int wr = wave >> 1, wc = wave & 1;
  int quad = lane >> 4, ml = lane & 15;
  int m0 = blockIdx.y * 128, n0 = blockIdx.x * 128;
  f32x4 acc[4][4] = {{{0.f,0.f,0.f,0.f}}};
#pragma unroll
  for (int rt = 0; rt < 4; ++rt)
#pragma unroll
    for (int ct = 0; ct < 4; ++ct)
#pragma unroll
      for (int r = 0; r < 4; ++r) acc[rt][ct][r] = 0.f;

  for (int k0 = 0; k0 < K; k0 += 32) {
    __syncthreads();                       // previous-iter LDS reads done
#pragma unroll
    for (int i = 0; i < 2; ++i) {
      int c = tid + i * 256;               // 512 16B-chunks per operand tile
      int row = c >> 2, kg = (c & 3) * 8;
      *(uint4*)&As[row * 40 + kg] = *(const uint4*)&A[(size_t)(m0 + row) * K + k0 + kg];
      *(uint4*)&Bs[row * 40 + kg] = *(const uint4*)&Bt[(size_t)(n0 + row) * K + k0 + kg];
    }
    __syncthreads();
    short8 af[4], bfr[4];
#pragma unroll
    for (int rt = 0; rt < 4; ++rt)
      af[rt] = *(const short8*)&As[(wr * 64 + rt * 16 + ml) * 40 + quad * 8];
#pragma unroll
    for (int ct = 0; ct < 4; ++ct)
      bfr[ct] = *(const short8*)&Bs[(wc * 64 + ct * 16 + ml) * 40 + quad * 8];
#pragma unroll
    for (int rt = 0; rt < 4; ++rt)
#pragma unroll
      for (int ct = 0; ct < 4; ++ct)
        acc[rt][ct] = __builtin_amdgcn_mfma_f32_16x16x32_bf16(af[rt], bfr[ct], acc[rt][ct], 0, 0, 0);
  }
  // C/D layout (verified m89/m91): col = lane&15, row = quad*4 + reg
#pragma unroll
  for (int rt = 0; rt < 4; ++rt)
#pragma unroll
    for (int ct = 0; ct < 4; ++ct)
#pragma unroll
      for (int r = 0; r < 4; ++r) {
        int grow = m0 + wr * 64 + rt * 16 + quad * 4 + r;
        int gcol = n0 + wc * 64 + ct * 16 + ml;
        C[(size_t)grow * N + gcol] = f2b(acc[rt][ct][r]);
      }
}

// ---------------- attention coefficients al/ar: (N,8) ----------------
__global__ __launch_bounds__(256) void k_attn(const bf16* __restrict__ H, const void* __restrict__ a_s,
                                              const void* __restrict__ a_d, float* __restrict__ al,
                                              float* __restrict__ ar, int C, const int* __restrict__ flags) {
  int wF = flags[1];
  int n = blockIdx.x;
  int lane = threadIdx.x & 63, wave = threadIdx.x >> 6;
  int D = 8 * C;
#pragma unroll
  for (int u = 0; u < 2; ++u) {
    int hd = wave * 2 + u;
    float ps = 0.f, pd = 0.f;
    for (int c = lane; c < C; c += 64) {
      float h = b2f(H[(size_t)n * D + hd * C + c]);
      ps = fmaf(h, ldsel(a_s, hd * C + c, wF), ps);
      pd = fmaf(h, ldsel(a_d, hd * C + c, wF), pd);
    }
#pragma unroll
    for (int off = 32; off; off >>= 1) { ps += __shfl_down(ps, off); pd += __shfl_down(pd, off); }
    if (lane == 0) { al[n * 8 + hd] = ps; ar[n * 8 + hd] = pd; }
  }
}

// ---------------- per-dst softmax + aggregation + bias + ELU + LayerNorm ----------------
__global__ __launch_bounds__(256) void k_agg(const bf16* __restrict__ H, const float* __restrict__ al,
                                             const float* __restrict__ ar, const int* __restrict__ cnt,
                                             const int* __restrict__ bucket, const void* __restrict__ bias,
                                             const void* __restrict__ ls, const void* __restrict__ lb,
                                             bf16* __restrict__ Xout, int C, int concat,
                                             const int* __restrict__ flags) {
  int wF = flags[1];
  int d = blockIdx.x;
  int t = threadIdx.x;
  int lane = t & 63, wave = t >> 6;
  int D = 8 * C;
  __shared__ int sid[MAXDEG + 1];
  __shared__ float w[8][MAXDEG + 2];
  __shared__ float vals[2048];
  __shared__ float r1[4], r2[4];
  __shared__ float sMu, sRs;

  int deg = cnt[d]; deg = deg > MAXDEG ? MAXDEG : deg;
  if (t < deg) sid[t] = bucket[d * MAXDEG + t];
  if (t == deg) sid[deg] = d;                 // self loop (PyG appends it always)
  __syncthreads();
  int total = deg + 1;

  if (t < 8) {   // per-head segment softmax over incoming edges
    float ard = ar[d * 8 + t];
    float m = -1e30f;
    for (int e = 0; e < total; ++e) {
      float lg = al[sid[e] * 8 + t] + ard;
      lg = lg > 0.f ? lg : 0.2f * lg;         // leaky_relu(0.2)
      w[t][e] = lg;
      m = fmaxf(m, lg);
    }
    float den = 0.f;
    for (int e = 0; e < total; ++e) { float x = expf(w[t][e] - m); w[t][e] = x; den += x; }
    float inv = 1.f / den;
    for (int e = 0; e < total; ++e) w[t][e] *= inv;
  }
  __syncthreads();

  for (int i = t; i < D; i += 256) {
    int hd = i / C;
    float acc = 0.f;
    for (int e = 0; e < total; ++e) acc = fmaf(w[hd][e], b2f(H[(size_t)sid[e] * D + i]), acc);
    vals[i] = acc;
  }
  __syncthreads();

  if (concat) {
    float loc[8];
    float s1 = 0.f, s2 = 0.f;
    int nl = 0;
    for (int i = t; i < D; i += 256) {
      float v = vals[i] + ldsel(bias, i, wF);
      v = v > 0.f ? v : expf(v) - 1.f;        // ELU
      loc[nl++] = v; s1 += v; s2 += v * v;
    }
#pragma unroll
    for (int off = 32; off; off >>= 1) { s1 += __shfl_down(s1, off); s2 += __shfl_down(s2, off); }
    if (lane == 0) { r1[wave] = s1; r2[wave] = s2; }
    __syncthreads();
    if (t == 0) {
      float S1 = r1[0] + r1[1] + r1[2] + r1[3];
      float S2 = r2[0] + r2[1] + r2[2] + r2[3];
      float mu = S1 / D;
      sMu = mu; sRs = rsqrtf(S2 / D - mu * mu + 1e-5f);
    }
    __syncthreads();
    nl = 0;
    for (int i = t; i < D; i += 256) {
      float v = loc[nl++];
      Xout[(size_t)d * D + i] = f2b((v - sMu) * sRs * ldsel(ls, i, wF) + ldsel(lb, i, wF));
    }
  } else {
    if (t < 64) {   // wave 0: mean over 8 heads -> 64 dims, ELU, LN over 64
      float v = 0.f;
#pragma unroll
      for (int h = 0; h < 8; ++h) v += vals[h * 64 + t];
      v = v * 0.125f + ldsel(bias, t, wF);
      v = v > 0.f ? v : expf(v) - 1.f;
      float s1 = v, s2 = v * v;
#pragma unroll
      for (int off = 32; off; off >>= 1) { s1 += __shfl_xor(s1, off); s2 += __shfl_xor(s2, off); }
      float mu = s1 * (1.f / 64.f);
      float var = s2 * (1.f / 64.f) - mu * mu;
      float rs = rsqrtf(var + 1e-5f);
      Xout[(size_t)d * 64 + t] = f2b((v - mu) * rs * ldsel(ls, t, wF) + ldsel(lb, t, wF));
    }
  }
}

// ---------------- projection (64->256) + LN + GELU(erf) + q ----------------
__global__ __launch_bounds__(256) void k_proj(const bf16* __restrict__ X3, const void* __restrict__ wp,
                                              const void* __restrict__ bp, const void* __restrict__ lsp,
                                              const void* __restrict__ lbp, const void* __restrict__ wq,
                                              const void* __restrict__ bq,
                                              float* __restrict__ q, void* __restrict__ dout,
                                              const int* __restrict__ flags) {
  int wF = flags[1], xF = flags[0];
  int n = blockIdx.x, t = threadIdx.x;
  int lane = t & 63, wave = t >> 6;
  __shared__ float xs[64];
  __shared__ float r1[4], r2[4];
  __shared__ float sMu, sRs;
  if (t < 64) xs[t] = b2f(X3[n * 64 + t]);
  __syncthreads();
  float y = ldsel(bp, t, wF);
#pragma unroll 8
  for (int k = 0; k < 64; ++k) y = fmaf(xs[k], ldsel(wp, k * 256 + t, wF), y);
  float s1 = y, s2 = y * y;
#pragma unroll
  for (int off = 32; off; off >>= 1) { s1 += __shfl_down(s1, off); s2 += __shfl_down(s2, off); }
  if (lane == 0) { r1[wave] = s1; r2[wave] = s2; }
  __syncthreads();
  if (t == 0) {
    float S1 = r1[0] + r1[1] + r1[2] + r1[3];
    float S2 = r2[0] + r2[1] + r2[2] + r2[3];
    float mu = S1 / 256.f;
    sMu = mu; sRs = rsqrtf(S2 / 256.f - mu * mu + 1e-5f);
  }
  __syncthreads();
  float v = (y - sMu) * sRs * ldsel(lsp, t, wF) + ldsel(lbp, t, wF);
  float g = 0.5f * v * (1.f + erff(v * 0.70710678118654752f));   // exact GELU
  stsel(dout, (size_t)NG * 256 + (size_t)n * 256 + t, g, xF);    // node_out
  float qv = g * ldsel(wq, t, wF);
#pragma unroll
  for (int off = 32; off; off >>= 1) qv += __shfl_down(qv, off);
  if (lane == 0) r1[wave] = qv;
  __syncthreads();
  if (t == 0) q[n] = r1[0] + r1[1] + r1[2] + r1[3] + ldsel(bq, 0, wF);
}

// ---------------- attention pooling per graph ----------------
__global__ __launch_bounds__(256) void k_pool(void* __restrict__ dout, const float* __restrict__ q,
                                              const int* __restrict__ flags) {
  int xF = flags[0];
  int b = blockIdx.x, t = threadIdx.x;
  __shared__ float es[NREG];
  __shared__ float sDen;
  if (t < NREG) es[t] = q[b * NREG + t];
  __syncthreads();
  if (t == 0) {
    float m = -1e30f;
    for (int i = 0; i < NREG; ++i) m = fmaxf(m, es[i]);
    float den = 0.f;
    for (int i = 0; i < NREG; ++i) { float e = expf(es[i] - m); es[i] = e; den += e; }
    sDen = den;
  }
  __syncthreads();
  float acc = 0.f;
  for (int i = 0; i < NREG; ++i)
    acc = fmaf(es[i], ldsel(dout, (size_t)NG * 256 + (size_t)(b * NREG + i) * 256 + t, xF), acc);
  stsel(dout, (size_t)b * 256 + t, acc / sDen, xF);
}

// ---------------- launcher ----------------
extern "C" void kernel_launch(void* const* d_in, const int* in_sizes, int n_in,
                              void* d_out, int out_size, void* d_ws, size_t ws_size,
                              hipStream_t stream) {
  const void* nf  = d_in[0];
  const int* src  = (const int*)d_in[1];
  const int* dst  = (const int*)d_in[2];
  const void *w0 = d_in[4],  *b0 = d_in[5],  *as0 = d_in[6], *ad0 = d_in[7],  *ls0 = d_in[8],  *lb0 = d_in[9];
  const void *w1 = d_in[10], *b1 = d_in[11], *as1 = d_in[12], *ad1 = d_in[13], *ls1 = d_in[14], *lb1 = d_in[15];
  const void *w2 = d_in[16], *b2 = d_in[17], *as2 = d_in[18], *ad2 = d_in[19], *ls2 = d_in[20], *lb2 = d_in[21];
  const void *wp = d_in[22], *bp = d_in[23], *lsp = d_in[24], *lbp = d_in[25], *wq = d_in[26], *bq = d_in[27];

  // workspace layout — TOTAL ~31.4 MB (same as passing R2 layout)
  int* flags  = (int*)d_ws;                       // 4 ints (16 B)
  float* al   = (float*)(flags + 4);              // NN*8 f32
  float* ar   = al + NN * 8;
  int* cnt    = (int*)(ar + NN * 8);              // NN
  int* bucket = cnt + NN;                         // NN*MAXDEG
  float* q    = (float*)(bucket + NN * MAXDEG);   // NN f32
  bf16* X     = (bf16*)(q + NN);                  // NN*2048 bf16 (16B-aligned)
  bf16* Hb    = X + (size_t)NN * 2048;            // NN*2048 bf16

  // dead-region reuse for bf16 staging buffers:
  bf16* X0  = X;                          // NN*256 bf16 input copy (dead after gemm0)
  bf16* wt0 = X + (1 << 20);              // 2048*256  (dead after gemm0; agg0 then overwrites X)
  bf16* wt1 = Hb + (size_t)NN * 1024;     // 1024*2048 in upper half of Hb (gemm1 writes lower half)
  bf16* wt2 = Hb + (size_t)NN * 512;      // 512*1024  above gemm2's output region

  // stage 0: dtype detect, edge buckets, input conversion
  k_detect<<<1, 256, 0, stream>>>(nf, w0, flags);
  k_zero<<<(NN + 255) / 256, 256, 0, stream>>>(cnt, NN);
  k_scatter<<<(NE + 255) / 256, 256, 0, stream>>>(src, dst, cnt, bucket, NE);
  k_tobf16<<<(NN * 256 + 255) / 256, 256, 0, stream>>>(nf, X0, NN * 256, flags, 0);

  // layer 0: 256 -> 8x256 concat (2048)
  k_transpose<<<dim3(256 / 32, 2048 / 32), 256, 0, stream>>>(w0, wt0, 256, 2048, flags);
  k_gemm_mfma<<<dim3(2048 / 128, NN / 128), 256, 0, stream>>>(X0, wt0, Hb, NN, 2048, 256);
  k_attn<<<NN, 256, 0, stream>>>(Hb, as0, ad0, al, ar, 256, flags);
  k_agg<<<NN, 256, 0, stream>>>(Hb, al, ar, cnt, bucket, b0, ls0, lb0, X, 256, 1, flags);

  // layer 1: 2048 -> 8x128 concat (1024)
  k_transpose<<<dim3(2048 / 32, 1024 / 32), 256, 0, stream>>>(w1, wt1, 2048, 1024, flags);
  k_gemm_mfma<<<dim3(1024 / 128, NN / 128), 256, 0, stream>>>(X, wt1, Hb, NN, 1024, 2048);
  k_attn<<<NN, 256, 0, stream>>>(Hb, as1, ad1, al, ar, 128, flags);
  k_agg<<<NN, 256, 0, stream>>>(Hb, al, ar, cnt, bucket, b1, ls1, lb1, X, 128, 1, flags);

  // layer 2: 1024 -> 8x64 mean (64)
  k_transpose<<<dim3(1024 / 32, 512 / 32), 256, 0, stream>>>(w2, wt2, 1024, 512, flags);
  k_gemm_mfma<<<dim3(512 / 128, NN / 128), 256, 0, stream>>>(X, wt2, Hb, NN, 512, 1024);
  k_attn<<<NN, 256, 0, stream>>>(Hb, as2, ad2, al, ar, 64, flags);
  k_agg<<<NN, 256, 0, stream>>>(Hb, al, ar, cnt, bucket, b2, ls2, lb2, X, 64, 0, flags);

  // projection + GELU + q, then pooling (node_out lives in d_out)
  k_proj<<<NN, 256, 0, stream>>>(X, wp, bp, lsp, lbp, wq, bq, q, d_out, flags);
  k_pool<<<NG, 256, 0, stream>>>(d_out, q, flags);
}